// Round 1
// baseline (1275.109 us; speedup 1.0000x reference)
//
#include <hip/hip_runtime.h>
#include <math.h>

#define B 32
#define C 256
#define M 64
#define N 4096  // H*W

static constexpr float EPS = 1e-12f;

// ---------------------------------------------------------------------------
// K1: logits S[b][m][n] = sum_c W[m,c] * x[b,c,n]
// thread = pixel n; acc[M] in VGPRs; W loads are wave-uniform -> s_load.
// ---------------------------------------------------------------------------
__global__ __launch_bounds__(256) void k1_logits(const float* __restrict__ x,
                                                 const float* __restrict__ Wm,
                                                 float* __restrict__ S) {
    const int n = blockIdx.x * 256 + threadIdx.x;
    const int b = blockIdx.y;
    const float* xb = x + (size_t)b * C * N + n;
    float acc[M];
#pragma unroll
    for (int m = 0; m < M; ++m) acc[m] = 0.f;
    for (int c0 = 0; c0 < C; c0 += 16) {
        float xv[16];
#pragma unroll
        for (int cc = 0; cc < 16; ++cc) xv[cc] = xb[(size_t)(c0 + cc) * N];
#pragma unroll
        for (int m = 0; m < M; ++m) {
            float a = acc[m];
#pragma unroll
            for (int cc = 0; cc < 16; ++cc) a += xv[cc] * Wm[m * C + c0 + cc];
            acc[m] = a;
        }
    }
    float* Sb = S + (size_t)b * M * N + n;
#pragma unroll
    for (int m = 0; m < M; ++m) Sb[(size_t)m * N] = acc[m];
}

// ---------------------------------------------------------------------------
// K2: softmax over n (4096) for each (b,m) column; in place.
// ---------------------------------------------------------------------------
__global__ __launch_bounds__(256) void k2_softmax_n(float* __restrict__ S) {
    const int m = blockIdx.x, b = blockIdx.y;
    float* col = S + ((size_t)b * M + m) * N;
    const int t = threadIdx.x;
    float v[16];
    float mx = -INFINITY;
#pragma unroll
    for (int i = 0; i < 16; ++i) {
        v[i] = col[t + i * 256];
        mx = fmaxf(mx, v[i]);
    }
#pragma unroll
    for (int off = 32; off >= 1; off >>= 1) mx = fmaxf(mx, __shfl_xor(mx, off));
    __shared__ float redm[4];
    const int wave = t >> 6, lane = t & 63;
    if (lane == 0) redm[wave] = mx;
    __syncthreads();
    mx = fmaxf(fmaxf(redm[0], redm[1]), fmaxf(redm[2], redm[3]));
    float s = 0.f;
#pragma unroll
    for (int i = 0; i < 16; ++i) {
        v[i] = __expf(v[i] - mx);
        s += v[i];
    }
#pragma unroll
    for (int off = 32; off >= 1; off >>= 1) s += __shfl_xor(s, off);
    __shared__ float reds[4];
    if (lane == 0) reds[wave] = s;
    __syncthreads();
    s = reds[0] + reds[1] + reds[2] + reds[3];
    const float inv = 1.f / s;
#pragma unroll
    for (int i = 0; i < 16; ++i) col[t + i * 256] = v[i] * inv;
}

// ---------------------------------------------------------------------------
// K3a: partial proto: parts[b][ck][m][c] = sum_{n in chunk ck} P[b][m][n]*x[b][c][n]
// thread = c; x tile staged in LDS (padded stride 33 -> 2-way bank, free);
// P loads are uniform -> s_load.
// ---------------------------------------------------------------------------
__global__ __launch_bounds__(256) void k3a_proto_part(const float* __restrict__ x,
                                                      const float* __restrict__ P,
                                                      float* __restrict__ parts) {
    const int ck = blockIdx.x, b = blockIdx.y;
    const int tid = threadIdx.x;  // = c
    __shared__ float xs[256 * 33];
    float acc[M];
#pragma unroll
    for (int m = 0; m < M; ++m) acc[m] = 0.f;
    const float* xb = x + (size_t)b * C * N;
    const float* Pb = P + (size_t)b * M * N;
    const int n0 = ck * 256;
    for (int sub = 0; sub < 8; ++sub) {
        const int ns = n0 + sub * 32;
#pragma unroll
        for (int i = 0; i < 32; ++i) {
            int idx = tid + i * 256;  // 0..8191 -> (c = idx>>5, j = idx&31)
            int c = idx >> 5, j = idx & 31;
            xs[c * 33 + j] = xb[(size_t)c * N + ns + j];
        }
        __syncthreads();
        float xvv[32];
#pragma unroll
        for (int j = 0; j < 32; ++j) xvv[j] = xs[tid * 33 + j];
#pragma unroll
        for (int m = 0; m < M; ++m) {
            float a = acc[m];
#pragma unroll
            for (int j = 0; j < 32; ++j) a += Pb[(size_t)m * N + ns + j] * xvv[j];
            acc[m] = a;
        }
        __syncthreads();
    }
    float* pp = parts + (((size_t)b * 16 + ck) * M) * C + tid;
#pragma unroll
    for (int m = 0; m < M; ++m) pp[(size_t)m * C] = acc[m];
}

// ---------------------------------------------------------------------------
// K3b: reduce 16 partials, L2-normalize -> proto[b][m][c]; p2[b][m] = |proto|^2
// ---------------------------------------------------------------------------
__global__ __launch_bounds__(256) void k3b_reduce(const float* __restrict__ parts,
                                                  float* __restrict__ proto,
                                                  float* __restrict__ p2) {
    const int m = blockIdx.x, b = blockIdx.y, c = threadIdx.x;
    float v = 0.f;
#pragma unroll
    for (int ck = 0; ck < 16; ++ck)
        v += parts[(((size_t)b * 16 + ck) * M + m) * C + c];
    float sq = v * v;
#pragma unroll
    for (int off = 32; off >= 1; off >>= 1) sq += __shfl_xor(sq, off);
    __shared__ float red[4];
    const int wave = c >> 6, lane = c & 63;
    if (lane == 0) red[wave] = sq;
    __syncthreads();
    const float ssq = red[0] + red[1] + red[2] + red[3];
    const float nrm = sqrtf(ssq);
    const float denom = fmaxf(nrm, EPS);
    proto[((size_t)b * M + m) * C + c] = v / denom;
    if (c == 0) p2[b * M + m] = ssq / (denom * denom);
}

// ---------------------------------------------------------------------------
// K4a: raw scores s[m] = tok . proto[m]; softmax over m (in-register);
// writes p[b][m][n]; compact-loss block partials via
// sum_c (tok-pos)^2 = sum x^2 - 2*max_m s + p2[top1].
// ---------------------------------------------------------------------------
__global__ __launch_bounds__(256) void k4a_score(const float* __restrict__ x,
                                                 const float* __restrict__ proto,
                                                 const float* __restrict__ p2,
                                                 float* __restrict__ pbuf,
                                                 float* __restrict__ cparts) {
    const int n = blockIdx.x * 256 + threadIdx.x;
    const int b = blockIdx.y;
    const float* xb = x + (size_t)b * C * N + n;
    const float* pr = proto + (size_t)b * M * C;
    float acc[M];
#pragma unroll
    for (int m = 0; m < M; ++m) acc[m] = 0.f;
    float xsq = 0.f;
    for (int c0 = 0; c0 < C; c0 += 16) {
        float xv[16];
#pragma unroll
        for (int cc = 0; cc < 16; ++cc) xv[cc] = xb[(size_t)(c0 + cc) * N];
#pragma unroll
        for (int cc = 0; cc < 16; ++cc) xsq += xv[cc] * xv[cc];
#pragma unroll
        for (int m = 0; m < M; ++m) {
            float a = acc[m];
#pragma unroll
            for (int cc = 0; cc < 16; ++cc) a += xv[cc] * pr[m * C + c0 + cc];
            acc[m] = a;
        }
    }
    float smax = acc[0];
    int t1 = 0;
#pragma unroll
    for (int m = 1; m < M; ++m)
        if (acc[m] > smax) { smax = acc[m]; t1 = m; }
    const float p2t = p2[b * M + t1];
    float cpix = xsq - 2.f * smax + p2t;
    float s = 0.f;
#pragma unroll
    for (int m = 0; m < M; ++m) {
        acc[m] = __expf(acc[m] - smax);
        s += acc[m];
    }
    const float inv = 1.f / s;
    float* pb = pbuf + (size_t)b * M * N + n;
#pragma unroll
    for (int m = 0; m < M; ++m) pb[(size_t)m * N] = acc[m] * inv;
    // block-reduce compact partial (deterministic: per-block slot)
#pragma unroll
    for (int off = 32; off >= 1; off >>= 1) cpix += __shfl_xor(cpix, off);
    __shared__ float red[4];
    const int wave = threadIdx.x >> 6, lane = threadIdx.x & 63;
    if (lane == 0) red[wave] = cpix;
    __syncthreads();
    if (threadIdx.x == 0)
        cparts[blockIdx.y * 16 + blockIdx.x] = red[0] + red[1] + red[2] + red[3];
}

// ---------------------------------------------------------------------------
// K4b: new_query[n][c] = sum_m p[m] proto[m][c], L2-normalized over c,
// stored transposed as out[b][c][n]. Block = 64 pixels x 4 c-chunk waves.
// ---------------------------------------------------------------------------
__global__ __launch_bounds__(256) void k4b_newquery(const float* __restrict__ proto,
                                                    const float* __restrict__ pbuf,
                                                    float* __restrict__ out) {
    const int b = blockIdx.y;
    const int lane = threadIdx.x & 63;
    const int cq = __builtin_amdgcn_readfirstlane(threadIdx.x >> 6);
    const int n = blockIdx.x * 64 + lane;
    const float* pr = proto + (size_t)b * M * C + cq * 64;
    const float* pb = pbuf + (size_t)b * M * N + n;
    float acc[64];
#pragma unroll
    for (int i = 0; i < 64; ++i) acc[i] = 0.f;
    for (int m = 0; m < M; ++m) {
        const float pm = pb[(size_t)m * N];
#pragma unroll
        for (int cc = 0; cc < 64; ++cc) acc[cc] += pm * pr[m * C + cc];
    }
    float ssq = 0.f;
#pragma unroll
    for (int cc = 0; cc < 64; ++cc) ssq += acc[cc] * acc[cc];
    __shared__ float ss[4][64];
    ss[cq][lane] = ssq;
    __syncthreads();
    const float tot = ss[0][lane] + ss[1][lane] + ss[2][lane] + ss[3][lane];
    const float scale = 1.f / fmaxf(sqrtf(tot), EPS);
    float* ob = out + (size_t)b * C * N + (size_t)(cq * 64) * N + n;
#pragma unroll
    for (int cc = 0; cc < 64; ++cc) ob[(size_t)cc * N] = acc[cc] * scale;
}

// ---------------------------------------------------------------------------
// K5: distance loss partials per (b, pair-chunk). Proto staged in LDS with
// XOR swizzle (conflict-free column access).
// ---------------------------------------------------------------------------
__global__ __launch_bounds__(256) void k5_dis(const float* __restrict__ proto,
                                              const float* __restrict__ p2,
                                              float* __restrict__ dparts) {
    const int q = blockIdx.x;  // 0..7 pair chunk
    const int b = blockIdx.y;
    const float* pr = proto + (size_t)b * M * C;
    __shared__ float pl[M * C];  // (m,c) at pl[m*256 + (c ^ (m&31))]
    for (int idx = threadIdx.x; idx < M * C; idx += 256) {
        int m = idx >> 8, c = idx & 255;
        pl[m * 256 + (c ^ (m & 31))] = pr[idx];
    }
    __syncthreads();
    float sum = 0.f;
    for (int k = 0; k < 2; ++k) {
        const int pair = q * 512 + k * 256 + threadIdx.x;
        const int i = pair >> 6, j = pair & 63;
        if (j > i) {
            float g = 0.f;
#pragma unroll 8
            for (int c = 0; c < C; ++c)
                g += pl[i * 256 + (c ^ (i & 31))] * pl[j * 256 + (c ^ (j & 31))];
            const float d = 1.f - (p2[b * M + i] + p2[b * M + j] - 2.f * g);
            sum += fmaxf(d, 0.f);
        }
    }
#pragma unroll
    for (int off = 32; off >= 1; off >>= 1) sum += __shfl_xor(sum, off);
    __shared__ float red[4];
    const int wave = threadIdx.x >> 6, lane = threadIdx.x & 63;
    if (lane == 0) red[wave] = sum;
    __syncthreads();
    if (threadIdx.x == 0) dparts[b * 8 + q] = red[0] + red[1] + red[2] + red[3];
}

// ---------------------------------------------------------------------------
// K6: deterministic final reduce of the two loss scalars.
// ---------------------------------------------------------------------------
__global__ __launch_bounds__(256) void k6_final(const float* __restrict__ cparts,
                                                const float* __restrict__ dparts,
                                                float* __restrict__ losses) {
    const int t = threadIdx.x;
    float cs = cparts[t] + cparts[t + 256];
    float ds = dparts[t];
#pragma unroll
    for (int off = 32; off >= 1; off >>= 1) {
        cs += __shfl_xor(cs, off);
        ds += __shfl_xor(ds, off);
    }
    __shared__ float rc[4], rd[4];
    const int wave = t >> 6, lane = t & 63;
    if (lane == 0) { rc[wave] = cs; rd[wave] = ds; }
    __syncthreads();
    if (t == 0) {
        const float ctot = rc[0] + rc[1] + rc[2] + rc[3];
        const float dtot = rd[0] + rd[1] + rd[2] + rd[3];
        losses[0] = ctot / ((float)B * (float)N * (float)C);
        losses[1] = dtot * (2.f / (float)(M * (M - 1))) / (float)B;
    }
}

extern "C" void kernel_launch(void* const* d_in, const int* in_sizes, int n_in,
                              void* d_out, int out_size, void* d_ws, size_t ws_size,
                              hipStream_t stream) {
    const float* x = (const float*)d_in[0];
    const float* Wm = (const float*)d_in[1];
    // d_in[2] (label_batch) is unused by the reference outputs.
    float* out = (float*)d_out;

    // ws layout (floats): S[B*M*N] | proto[B*M*C] | p2[B*M] | cparts[512] | dparts[256]
    float* S = (float*)d_ws;                 // 8,388,608
    float* proto = S + (size_t)B * M * N;    //   524,288
    float* p2 = proto + (size_t)B * M * C;   //     2,048
    float* cparts = p2 + (size_t)B * M;      //       512
    float* dparts = cparts + 512;            //       256

    // proto partials exactly fill d_out[0 .. B*M*N*... ] region (8,388,608 floats),
    // consumed by k3b before k4b overwrites d_out with the real output.
    float* parts = out;
    float* losses = out + (size_t)B * C * N;  // the two scalar outputs

    k1_logits<<<dim3(N / 256, B), 256, 0, stream>>>(x, Wm, S);
    k2_softmax_n<<<dim3(M, B), 256, 0, stream>>>(S);
    k3a_proto_part<<<dim3(16, B), 256, 0, stream>>>(x, S, parts);
    k3b_reduce<<<dim3(M, B), 256, 0, stream>>>(parts, proto, p2);
    k4a_score<<<dim3(N / 256, B), 256, 0, stream>>>(x, proto, p2, S, cparts);
    k4b_newquery<<<dim3(N / 64, B), 256, 0, stream>>>(proto, S, out);
    k5_dis<<<dim3(8, B), 256, 0, stream>>>(proto, p2, dparts);
    k6_final<<<1, 256, 0, stream>>>(cparts, dparts, losses);
}

// Round 3
// 238.337 us; speedup vs baseline: 5.3500x; 5.3500x over previous
//
#include <hip/hip_runtime.h>
#include <math.h>

#define B 32
#define C 256
#define M 64
#define N 4096  // H*W

typedef __attribute__((ext_vector_type(8))) short s16x8;
typedef __attribute__((ext_vector_type(8))) __bf16 bf16x8;
typedef __attribute__((ext_vector_type(4))) float f32x4;
typedef __attribute__((ext_vector_type(4))) unsigned short u16x4;
typedef __attribute__((ext_vector_type(8))) unsigned short u16x8;

static constexpr float EPS = 1e-12f;

__device__ __forceinline__ unsigned short f2bf(float f) {
    unsigned u = __float_as_uint(f);
    u += 0x7FFFu + ((u >> 16) & 1u);  // RNE
    return (unsigned short)(u >> 16);
}
__device__ __forceinline__ float bf2f(unsigned short h) {
    return __uint_as_float((unsigned)h << 16);
}
__device__ __forceinline__ f32x4 MFMA(s16x8 a, s16x8 b, f32x4 c) {
    return __builtin_amdgcn_mfma_f32_16x16x32_bf16(
        __builtin_bit_cast(bf16x8, a), __builtin_bit_cast(bf16x8, b), c, 0, 0, 0);
}

// ---------------------------------------------------------------------------
// K0: x f32 [b][c][n] -> xb bf16 [b][c][n], xbt bf16 [b][n][c] (LDS transpose),
//     xsq[b][n] = sum_c x^2 (exact f32). One block per (64-n tile, b): 256 c.
// ---------------------------------------------------------------------------
__global__ __launch_bounds__(256) void k0_convert(const float* __restrict__ x,
                                                  unsigned short* __restrict__ xb,
                                                  unsigned short* __restrict__ xbt,
                                                  float* __restrict__ xsq) {
    const int nb = blockIdx.x, b = blockIdx.y;
    const int t = threadIdx.x;
    const int n = t & 63, cp = t >> 6;
    __shared__ unsigned short ts[256][66];  // [c][n] padded
    __shared__ float xp[4][64];
    float part = 0.f;
    const size_t xbase = (size_t)b * C * N + nb * 64;
#pragma unroll 8
    for (int i = 0; i < 64; ++i) {
        const int c = cp + i * 4;
        const float v = x[xbase + (size_t)c * N + n];
        part += v * v;
        const unsigned short h = f2bf(v);
        xb[xbase + (size_t)c * N + n] = h;
        ts[c][n] = h;
    }
    xp[cp][n] = part;
    __syncthreads();
    if (t < 64)
        xsq[(size_t)b * N + nb * 64 + t] = xp[0][t] + xp[1][t] + xp[2][t] + xp[3][t];
    const size_t tbase = ((size_t)b * N + nb * 64) * C;
#pragma unroll 8
    for (int i = 0; i < 64; ++i) {
        const int idx = t + i * 256;
        const int nn = idx >> 8, cc = idx & 255;
        xbt[tbase + (size_t)nn * C + cc] = ts[cc][nn];
    }
}

__global__ __launch_bounds__(256) void kW_convert(const float* __restrict__ Wf,
                                                  unsigned short* __restrict__ Wb) {
    const int i = blockIdx.x * 256 + threadIdx.x;  // M*C = 16384
    Wb[i] = f2bf(Wf[i]);
}

// ---------------------------------------------------------------------------
// K1: logits S[m][n] = sum_c W[m][c]*xbt[n][c]. MFMA D[aIdx=n][bIdx=m].
// ---------------------------------------------------------------------------
__global__ __launch_bounds__(256) void k1_mfma(const unsigned short* __restrict__ xbt,
                                               const unsigned short* __restrict__ Wb,
                                               unsigned short* __restrict__ Sb) {
    const int b = blockIdx.y;
    const int wv = threadIdx.x >> 6, lane = threadIdx.x & 63;
    const int li = lane & 15, lk = lane >> 4;
    const int n0 = blockIdx.x * 256 + wv * 64;
    const f32x4 zv = {0.f, 0.f, 0.f, 0.f};
    f32x4 acc[4][4];
#pragma unroll
    for (int s = 0; s < 4; ++s)
#pragma unroll
        for (int u = 0; u < 4; ++u) acc[s][u] = zv;
    const unsigned short* ar = xbt + ((size_t)b * N + n0 + li) * C + lk * 8;
    const unsigned short* br = Wb + (size_t)li * C + lk * 8;
#pragma unroll
    for (int c0 = 0; c0 < C; c0 += 32) {
        s16x8 af[4], bf_[4];
#pragma unroll
        for (int s = 0; s < 4; ++s) af[s] = *(const s16x8*)(ar + (size_t)s * 16 * C + c0);
#pragma unroll
        for (int u = 0; u < 4; ++u) bf_[u] = *(const s16x8*)(br + (size_t)u * 16 * C + c0);
#pragma unroll
        for (int s = 0; s < 4; ++s)
#pragma unroll
            for (int u = 0; u < 4; ++u) acc[s][u] = MFMA(af[s], bf_[u], acc[s][u]);
    }
    unsigned short* Srow = Sb + (size_t)b * M * N;
#pragma unroll
    for (int s = 0; s < 4; ++s)
#pragma unroll
        for (int u = 0; u < 4; ++u) {
            u16x4 h;
#pragma unroll
            for (int r = 0; r < 4; ++r) h[r] = f2bf(acc[s][u][r]);
            *(u16x4*)(Srow + (size_t)(u * 16 + li) * N + (n0 + s * 16 + lk * 4)) = h;
        }
}

// ---------------------------------------------------------------------------
// K2: softmax over n per (b,m); bf16 in -> bf16 out.
// ---------------------------------------------------------------------------
__global__ __launch_bounds__(256) void k2_softmax_n(const unsigned short* __restrict__ Sb,
                                                    unsigned short* __restrict__ Pb) {
    const int m = blockIdx.x, b = blockIdx.y;
    const unsigned short* col = Sb + ((size_t)b * M + m) * N;
    unsigned short* po = Pb + ((size_t)b * M + m) * N;
    const int t = threadIdx.x;
    float v[16];
    const u16x8 h0 = *(const u16x8*)(col + t * 16);
    const u16x8 h1 = *(const u16x8*)(col + t * 16 + 8);
#pragma unroll
    for (int i = 0; i < 8; ++i) v[i] = bf2f(h0[i]);
#pragma unroll
    for (int i = 0; i < 8; ++i) v[8 + i] = bf2f(h1[i]);
    float mx = -INFINITY;
#pragma unroll
    for (int i = 0; i < 16; ++i) mx = fmaxf(mx, v[i]);
#pragma unroll
    for (int off = 32; off >= 1; off >>= 1) mx = fmaxf(mx, __shfl_xor(mx, off));
    __shared__ float redm[4], reds[4];
    const int wave = t >> 6, lane = t & 63;
    if (lane == 0) redm[wave] = mx;
    __syncthreads();
    mx = fmaxf(fmaxf(redm[0], redm[1]), fmaxf(redm[2], redm[3]));
    float s = 0.f;
#pragma unroll
    for (int i = 0; i < 16; ++i) {
        v[i] = __expf(v[i] - mx);
        s += v[i];
    }
#pragma unroll
    for (int off = 32; off >= 1; off >>= 1) s += __shfl_xor(s, off);
    if (lane == 0) reds[wave] = s;
    __syncthreads();
    s = reds[0] + reds[1] + reds[2] + reds[3];
    const float inv = 1.f / s;
    u16x8 o0, o1;
#pragma unroll
    for (int i = 0; i < 8; ++i) o0[i] = f2bf(v[i] * inv);
#pragma unroll
    for (int i = 0; i < 8; ++i) o1[i] = f2bf(v[8 + i] * inv);
    *(u16x8*)(po + t * 16) = o0;
    *(u16x8*)(po + t * 16 + 8) = o1;
}

// ---------------------------------------------------------------------------
// K3: proto partials parts[b][ck][c][m] over 512-n chunks. D[aIdx=c][bIdx=m].
// ---------------------------------------------------------------------------
__global__ __launch_bounds__(256) void k3_mfma(const unsigned short* __restrict__ xb,
                                               const unsigned short* __restrict__ Pb,
                                               float* __restrict__ parts) {
    const int ck = blockIdx.x, b = blockIdx.y;  // ck in [0,8)
    const int wv = threadIdx.x >> 6, lane = threadIdx.x & 63;
    const int li = lane & 15, lk = lane >> 4;
    const int c0w = wv * 64;
    const int nb = ck * 512;
    const f32x4 zv = {0.f, 0.f, 0.f, 0.f};
    f32x4 acc[4][4];
#pragma unroll
    for (int s = 0; s < 4; ++s)
#pragma unroll
        for (int u = 0; u < 4; ++u) acc[s][u] = zv;
    const unsigned short* ar = xb + ((size_t)b * C + c0w + li) * N + nb + lk * 8;
    const unsigned short* br = Pb + ((size_t)b * M + li) * N + nb + lk * 8;
#pragma unroll 4
    for (int n0 = 0; n0 < 512; n0 += 32) {
        s16x8 af[4], bf_[4];
#pragma unroll
        for (int s = 0; s < 4; ++s) af[s] = *(const s16x8*)(ar + (size_t)s * 16 * N + n0);
#pragma unroll
        for (int u = 0; u < 4; ++u) bf_[u] = *(const s16x8*)(br + (size_t)u * 16 * N + n0);
#pragma unroll
        for (int s = 0; s < 4; ++s)
#pragma unroll
            for (int u = 0; u < 4; ++u) acc[s][u] = MFMA(af[s], bf_[u], acc[s][u]);
    }
    float* pp = parts + ((size_t)b * 8 + ck) * C * M;
#pragma unroll
    for (int s = 0; s < 4; ++s)
#pragma unroll
        for (int u = 0; u < 4; ++u)
#pragma unroll
            for (int r = 0; r < 4; ++r)
                pp[(size_t)(c0w + s * 16 + lk * 4 + r) * M + u * 16 + li] = acc[s][u][r];
}

// ---------------------------------------------------------------------------
// K3b: one block per b; thread t = c. Reduce 8 chunks; per-m norm via
// wave shfl butterflies + tiny LDS; write proto_bf [m][c] + protoT_bf [c][m]
// + p2. No big LDS.
// ---------------------------------------------------------------------------
__global__ __launch_bounds__(256) void k3b_reduce(const float* __restrict__ parts,
                                                  unsigned short* __restrict__ proto_bf,
                                                  unsigned short* __restrict__ protoT_bf,
                                                  float* __restrict__ p2) {
    const int b = blockIdx.x;
    const int t = threadIdx.x;  // = c
    const int wave = t >> 6, lane = t & 63;
    float v[M];
#pragma unroll
    for (int m = 0; m < M; ++m) v[m] = 0.f;
    const float* pb = parts + (size_t)b * 8 * C * M + (size_t)t * M;
    for (int ck = 0; ck < 8; ++ck) {
        const float* row = pb + (size_t)ck * C * M;
#pragma unroll
        for (int j = 0; j < 16; ++j) {
            const f32x4 q = *(const f32x4*)(row + j * 4);
            v[j * 4 + 0] += q[0];
            v[j * 4 + 1] += q[1];
            v[j * 4 + 2] += q[2];
            v[j * 4 + 3] += q[3];
        }
    }
    __shared__ float red[4][M];
#pragma unroll
    for (int m = 0; m < M; ++m) {
        float s = v[m] * v[m];
#pragma unroll
        for (int off = 32; off >= 1; off >>= 1) s += __shfl_xor(s, off);
        if (lane == 0) red[wave][m] = s;
    }
    __syncthreads();
    __shared__ float scl[M];
    if (t < M) {
        const float s = red[0][t] + red[1][t] + red[2][t] + red[3][t];
        const float denom = fmaxf(sqrtf(s), EPS);
        scl[t] = 1.f / denom;
        p2[b * M + t] = s / (denom * denom);
    }
    __syncthreads();
    unsigned short* prb = proto_bf + (size_t)b * M * C + t;
    unsigned short* prT = protoT_bf + ((size_t)b * C + t) * M;
    u16x8 hrow;
#pragma unroll
    for (int m = 0; m < M; ++m) {
        const unsigned short h = f2bf(v[m] * scl[m]);
        prb[(size_t)m * C] = h;
        hrow[m & 7] = h;
        if ((m & 7) == 7) *(u16x8*)(prT + (m & ~7)) = hrow;
    }
}

// ---------------------------------------------------------------------------
// K4a: raw scores sc[b][n][m] = sum_c xbt[n][c]*proto_bf[m][c]. f32 out.
// ---------------------------------------------------------------------------
__global__ __launch_bounds__(256) void k4a_mfma(const unsigned short* __restrict__ xbt,
                                                const unsigned short* __restrict__ proto_bf,
                                                float* __restrict__ sc) {
    const int b = blockIdx.y;
    const int wv = threadIdx.x >> 6, lane = threadIdx.x & 63;
    const int li = lane & 15, lk = lane >> 4;
    const int n0 = blockIdx.x * 256 + wv * 64;
    const f32x4 zv = {0.f, 0.f, 0.f, 0.f};
    f32x4 acc[4][4];
#pragma unroll
    for (int s = 0; s < 4; ++s)
#pragma unroll
        for (int u = 0; u < 4; ++u) acc[s][u] = zv;
    const unsigned short* ar = xbt + ((size_t)b * N + n0 + li) * C + lk * 8;
    const unsigned short* br = proto_bf + (size_t)b * M * C + (size_t)li * C + lk * 8;
#pragma unroll
    for (int c0 = 0; c0 < C; c0 += 32) {
        s16x8 af[4], bf_[4];
#pragma unroll
        for (int s = 0; s < 4; ++s) af[s] = *(const s16x8*)(ar + (size_t)s * 16 * C + c0);
#pragma unroll
        for (int u = 0; u < 4; ++u) bf_[u] = *(const s16x8*)(br + (size_t)u * 16 * C + c0);
#pragma unroll
        for (int s = 0; s < 4; ++s)
#pragma unroll
            for (int u = 0; u < 4; ++u) acc[s][u] = MFMA(af[s], bf_[u], acc[s][u]);
    }
    float* srow = sc + (size_t)b * N * M;
#pragma unroll
    for (int s = 0; s < 4; ++s)
#pragma unroll
        for (int u = 0; u < 4; ++u)
#pragma unroll
            for (int r = 0; r < 4; ++r)
                srow[(size_t)(n0 + s * 16 + lk * 4 + r) * M + u * 16 + li] = acc[s][u][r];
}

// ---------------------------------------------------------------------------
// K4c: softmax over m per pixel; top1 compact partials; pnm bf16 [b][n][m].
// ---------------------------------------------------------------------------
__global__ __launch_bounds__(256) void k4c_softmax_m(const float* __restrict__ sc,
                                                     const float* __restrict__ p2,
                                                     const float* __restrict__ xsq,
                                                     unsigned short* __restrict__ pnm,
                                                     float* __restrict__ cparts) {
    const int n = blockIdx.x * 256 + threadIdx.x;
    const int b = blockIdx.y;
    const float* srow = sc + ((size_t)b * N + n) * M;
    float v[M];
#pragma unroll
    for (int i = 0; i < 16; ++i) {
        const f32x4 q = *(const f32x4*)(srow + i * 4);
        v[i * 4 + 0] = q[0];
        v[i * 4 + 1] = q[1];
        v[i * 4 + 2] = q[2];
        v[i * 4 + 3] = q[3];
    }
    float smax = v[0];
    int t1 = 0;
#pragma unroll
    for (int j = 1; j < M; ++j)
        if (v[j] > smax) { smax = v[j]; t1 = j; }
    float cpix = xsq[(size_t)b * N + n] - 2.f * smax + p2[b * M + t1];
    float ssum = 0.f;
#pragma unroll
    for (int j = 0; j < M; ++j) {
        v[j] = __expf(v[j] - smax);
        ssum += v[j];
    }
    const float inv = 1.f / ssum;
    unsigned short* prow = pnm + ((size_t)b * N + n) * M;
#pragma unroll
    for (int i = 0; i < 8; ++i) {
        u16x8 h;
#pragma unroll
        for (int j = 0; j < 8; ++j) h[j] = f2bf(v[i * 8 + j] * inv);
        *(u16x8*)(prow + i * 8) = h;
    }
#pragma unroll
    for (int off = 32; off >= 1; off >>= 1) cpix += __shfl_xor(cpix, off);
    __shared__ float red[4];
    const int wave = threadIdx.x >> 6, lane = threadIdx.x & 63;
    if (lane == 0) red[wave] = cpix;
    __syncthreads();
    if (threadIdx.x == 0)
        cparts[b * 16 + blockIdx.x] = red[0] + red[1] + red[2] + red[3];
}

// ---------------------------------------------------------------------------
// K4b: out[b][c][n] = l2norm_c(sum_m protoT[c][m]*p[n][m]). D[aIdx=c][bIdx=n].
// ---------------------------------------------------------------------------
__global__ __launch_bounds__(256) void k4b_mfma(const unsigned short* __restrict__ protoT_bf,
                                                const unsigned short* __restrict__ pnm,
                                                float* __restrict__ out) {
    const int b = blockIdx.y;
    const int wv = threadIdx.x >> 6, lane = threadIdx.x & 63;
    const int li = lane & 15, lk = lane >> 4;
    const int n0 = blockIdx.x * 64;
    const int c0w = wv * 64;
    const f32x4 zv = {0.f, 0.f, 0.f, 0.f};
    f32x4 acc[4][4];  // [c-sub s][n-sub u]
#pragma unroll
    for (int s = 0; s < 4; ++s)
#pragma unroll
        for (int u = 0; u < 4; ++u) acc[s][u] = zv;
    const unsigned short* ar = protoT_bf + ((size_t)b * C + c0w + li) * M + lk * 8;
    const unsigned short* br = pnm + ((size_t)b * N + n0 + li) * M + lk * 8;
#pragma unroll
    for (int m0 = 0; m0 < M; m0 += 32) {
        s16x8 af[4], bf_[4];
#pragma unroll
        for (int s = 0; s < 4; ++s) af[s] = *(const s16x8*)(ar + (size_t)s * 16 * M + m0);
#pragma unroll
        for (int u = 0; u < 4; ++u) bf_[u] = *(const s16x8*)(br + (size_t)u * 16 * M + m0);
#pragma unroll
        for (int s = 0; s < 4; ++s)
#pragma unroll
            for (int u = 0; u < 4; ++u) acc[s][u] = MFMA(af[s], bf_[u], acc[s][u]);
    }
    float ssq[4];
#pragma unroll
    for (int u = 0; u < 4; ++u) {
        float s2 = 0.f;
#pragma unroll
        for (int s = 0; s < 4; ++s)
#pragma unroll
            for (int r = 0; r < 4; ++r) s2 += acc[s][u][r] * acc[s][u][r];
        s2 += __shfl_xor(s2, 16);
        s2 += __shfl_xor(s2, 32);
        ssq[u] = s2;
    }
    __shared__ float ls[4][4][16];
    if (lk == 0) {
#pragma unroll
        for (int u = 0; u < 4; ++u) ls[wv][u][li] = ssq[u];
    }
    __syncthreads();
    float scale[4];
#pragma unroll
    for (int u = 0; u < 4; ++u) {
        const float tot = ls[0][u][li] + ls[1][u][li] + ls[2][u][li] + ls[3][u][li];
        scale[u] = 1.f / fmaxf(sqrtf(tot), EPS);
    }
    float* ob = out + (size_t)b * C * N;
#pragma unroll
    for (int s = 0; s < 4; ++s)
#pragma unroll
        for (int u = 0; u < 4; ++u)
#pragma unroll
            for (int r = 0; r < 4; ++r)
                ob[(size_t)(c0w + s * 16 + lk * 4 + r) * N + n0 + u * 16 + li] =
                    acc[s][u][r] * scale[u];
}

// ---------------------------------------------------------------------------
// K5: distance loss partials; proto_bf staged to f32 LDS with XOR swizzle.
// ---------------------------------------------------------------------------
__global__ __launch_bounds__(256) void k5_dis(const unsigned short* __restrict__ proto_bf,
                                              const float* __restrict__ p2,
                                              float* __restrict__ dparts) {
    const int q = blockIdx.x;
    const int b = blockIdx.y;
    const unsigned short* pr = proto_bf + (size_t)b * M * C;
    __shared__ float pl[M * C];  // 64 KB
    for (int idx = threadIdx.x; idx < M * C; idx += 256) {
        int m = idx >> 8, c = idx & 255;
        pl[m * 256 + (c ^ (m & 31))] = bf2f(pr[idx]);
    }
    __syncthreads();
    float sum = 0.f;
    for (int k = 0; k < 2; ++k) {
        const int pair = q * 512 + k * 256 + threadIdx.x;
        const int i = pair >> 6, j = pair & 63;
        if (j > i) {
            float g = 0.f;
#pragma unroll 8
            for (int c = 0; c < C; ++c)
                g += pl[i * 256 + (c ^ (i & 31))] * pl[j * 256 + (c ^ (j & 31))];
            const float d = 1.f - (p2[b * M + i] + p2[b * M + j] - 2.f * g);
            sum += fmaxf(d, 0.f);
        }
    }
#pragma unroll
    for (int off = 32; off >= 1; off >>= 1) sum += __shfl_xor(sum, off);
    __shared__ float red[4];
    const int wave = threadIdx.x >> 6, lane = threadIdx.x & 63;
    if (lane == 0) red[wave] = sum;
    __syncthreads();
    if (threadIdx.x == 0) dparts[b * 8 + q] = red[0] + red[1] + red[2] + red[3];
}

__global__ __launch_bounds__(256) void k6_final(const float* __restrict__ cparts,
                                                const float* __restrict__ dparts,
                                                float* __restrict__ losses) {
    const int t = threadIdx.x;
    float cs = cparts[t] + cparts[t + 256];
    float ds = dparts[t];
#pragma unroll
    for (int off = 32; off >= 1; off >>= 1) {
        cs += __shfl_xor(cs, off);
        ds += __shfl_xor(ds, off);
    }
    __shared__ float rc[4], rd[4];
    const int wave = t >> 6, lane = t & 63;
    if (lane == 0) { rc[wave] = cs; rd[wave] = ds; }
    __syncthreads();
    if (t == 0) {
        const float ctot = rc[0] + rc[1] + rc[2] + rc[3];
        const float dtot = rd[0] + rd[1] + rd[2] + rd[3];
        losses[0] = ctot / ((float)B * (float)N * (float)C);
        losses[1] = dtot * (2.f / (float)(M * (M - 1))) / (float)B;
    }
}

extern "C" void kernel_launch(void* const* d_in, const int* in_sizes, int n_in,
                              void* d_out, int out_size, void* d_ws, size_t ws_size,
                              hipStream_t stream) {
    const float* x = (const float*)d_in[0];
    const float* Wf = (const float*)d_in[1];
    float* out = (float*)d_out;

    // ---- d_out as scratch (128 MB main region, all dead before k4b) ----
    // xbt bf16 [b][n][c]: floats [0, 16,777,216)          -- live k0..k4a
    // xb  bf16 [b][c][n]: floats [16,777,216, 33,554,432) -- live k0..k3
    // sc  f32  [b][n][m]: floats [16,777,216, 25,165,824) -- live k4a..k4c (over dead xb)
    unsigned short* xbt = (unsigned short*)d_out;
    unsigned short* xb = (unsigned short*)(out + (size_t)16777216);
    float* sc = out + (size_t)16777216;
    float* losses = out + (size_t)B * C * N;  // floats 33,554,432..33,554,434

    // ---- ws layout (floats), non-overlapping regions, 34.5 MB total ----
    float* wsf = (float*)d_ws;
    // region A [0, 4,194,304): Sbf bf16 (k1->k2), then parts f32 (k3->k3b)
    unsigned short* Sbf = (unsigned short*)wsf;
    float* parts = wsf;
    // region B [4,194,304, 8,388,608): Pbf bf16 (k2->k3), then pnm bf16 (k4c->k4b)
    unsigned short* Pbf = (unsigned short*)(wsf + 4194304);
    unsigned short* pnm = Pbf;
    // tail (sizes in floats): xsq 131,072 | proto_bf 262,144 | protoT_bf 262,144
    //                        | Wb 8,192 | p2 2,048 | cparts 512 | dparts 256
    float* xsq = wsf + 8388608;                                    // [8,388,608, 8,519,680)
    unsigned short* proto_bf = (unsigned short*)(wsf + 8519680);   // [8,519,680, 8,781,824)
    unsigned short* protoT_bf = (unsigned short*)(wsf + 8781824);  // [8,781,824, 9,043,968)
    unsigned short* Wb = (unsigned short*)(wsf + 9043968);         // [9,043,968, 9,052,160)
    float* p2 = wsf + 9052160;                                     // [9,052,160, 9,054,208)
    float* cparts = wsf + 9054208;                                 // [9,054,208, 9,054,720)
    float* dparts = wsf + 9054720;                                 // [9,054,720, 9,054,976)

    k0_convert<<<dim3(64, B), 256, 0, stream>>>(x, xb, xbt, xsq);
    kW_convert<<<dim3(64), 256, 0, stream>>>(Wf, Wb);
    k1_mfma<<<dim3(N / 256, B), 256, 0, stream>>>(xbt, Wb, Sbf);
    k2_softmax_n<<<dim3(M, B), 256, 0, stream>>>(Sbf, Pbf);
    k3_mfma<<<dim3(8, B), 256, 0, stream>>>(xb, Pbf, parts);
    k3b_reduce<<<dim3(B), 256, 0, stream>>>(parts, proto_bf, protoT_bf, p2);
    k4a_mfma<<<dim3(N / 256, B), 256, 0, stream>>>(xbt, proto_bf, sc);
    k4c_softmax_m<<<dim3(N / 256, B), 256, 0, stream>>>(sc, p2, xsq, pnm, cparts);
    k4b_mfma<<<dim3(N / 64, B), 256, 0, stream>>>(protoT_bf, pnm, out);
    k5_dis<<<dim3(8, B), 256, 0, stream>>>(proto_bf, p2, dparts);
    k6_final<<<1, 256, 0, stream>>>(cparts, dparts, losses);
}

// Round 4
// 177.988 us; speedup vs baseline: 7.1640x; 1.3391x over previous
//
#include <hip/hip_runtime.h>
#include <math.h>

#define B 32
#define C 256
#define M 64
#define N 4096  // H*W

typedef __attribute__((ext_vector_type(8))) short s16x8;
typedef __attribute__((ext_vector_type(8))) __bf16 bf16x8;
typedef __attribute__((ext_vector_type(4))) float f32x4;
typedef __attribute__((ext_vector_type(4))) unsigned short u16x4;
typedef __attribute__((ext_vector_type(8))) unsigned short u16x8;

static constexpr float EPS = 1e-12f;

__device__ __forceinline__ unsigned short f2bf(float f) {
    unsigned u = __float_as_uint(f);
    u += 0x7FFFu + ((u >> 16) & 1u);  // RNE
    return (unsigned short)(u >> 16);
}
__device__ __forceinline__ float bf2f(unsigned short h) {
    return __uint_as_float((unsigned)h << 16);
}
__device__ __forceinline__ f32x4 MFMA(s16x8 a, s16x8 b, f32x4 c) {
    return __builtin_amdgcn_mfma_f32_16x16x32_bf16(
        __builtin_bit_cast(bf16x8, a), __builtin_bit_cast(bf16x8, b), c, 0, 0, 0);
}
// hw-convert 8 f32 -> 8 bf16 (v_cvt_pk_bf16_f32, RNE)
__device__ __forceinline__ s16x8 cvt8(const f32x4 a, const f32x4 b) {
    bf16x8 h;
    h[0] = (__bf16)a[0]; h[1] = (__bf16)a[1]; h[2] = (__bf16)a[2]; h[3] = (__bf16)a[3];
    h[4] = (__bf16)b[0]; h[5] = (__bf16)b[1]; h[6] = (__bf16)b[2]; h[7] = (__bf16)b[3];
    return __builtin_bit_cast(s16x8, h);
}
// LDS column swizzle for the [n][c] bf16 tile (units: halfwords, flips bits 3-5 of c)
__device__ __forceinline__ int swz(int n) {
    return (((n >> 2) & 3) | ((n & 1) << 2)) << 3;
}

__global__ __launch_bounds__(256) void kW_convert(const float* __restrict__ Wf,
                                                  unsigned short* __restrict__ Wb) {
    const int i = blockIdx.x * 256 + threadIdx.x;  // M*C = 16384
    Wb[i] = f2bf(Wf[i]);
}

// ---------------------------------------------------------------------------
// K01: fused convert + transpose + logits.
//  - reads x f32 [b][c][n] tile (64 n x 256 c) with f32x4
//  - builds swizzled LDS tile tsT[n][c^sw(n)] bf16
//  - writes xbt bf16 [b][n][c] (u16x8, coalesced), xsq[b][n] (exact f32)
//  - computes S[b][m][n] = sum_c W[m][c]*x[n][c] via MFMA from LDS, bf16 out
// ---------------------------------------------------------------------------
__global__ __launch_bounds__(256) void k01(const float* __restrict__ x,
                                           const unsigned short* __restrict__ Wb,
                                           unsigned short* __restrict__ xbt,
                                           unsigned short* __restrict__ Sb,
                                           float* __restrict__ xsq) {
    const int nb = blockIdx.x, b = blockIdx.y;
    const int t = threadIdx.x;
    __shared__ unsigned short tsT[64 * 256];
    __shared__ float xred[16][68];
    // ---- phase A: load/convert/stage ----
    const int g = t & 15, cp = t >> 4;  // g: n-quad, cp: c-group
    float part[4] = {0.f, 0.f, 0.f, 0.f};
    const float* xrow = x + (size_t)b * C * N + (size_t)nb * 64 + 4 * g;
#pragma unroll
    for (int i = 0; i < 16; ++i) {
        const int c = cp + 16 * i;
        const f32x4 q = *(const f32x4*)(xrow + (size_t)c * N);
#pragma unroll
        for (int k = 0; k < 4; ++k) {
            const float v = q[k];
            part[k] += v * v;
            const int n = 4 * g + k;
            tsT[n * 256 + (c ^ swz(n))] = f2bf(v);
        }
    }
#pragma unroll
    for (int k = 0; k < 4; ++k) xred[cp][4 * g + k] = part[k];
    __syncthreads();
    if (t < 64) {
        float s = 0.f;
#pragma unroll
        for (int j = 0; j < 16; ++j) s += xred[j][t];
        xsq[(size_t)b * N + nb * 64 + t] = s;
    }
    // ---- phase B1: xbt coalesced write ----
    {
        const int l = t & 31, nh = t >> 5;
#pragma unroll
        for (int j = 0; j < 8; ++j) {
            const int n = nh + 8 * j;
            const int c0 = l * 8;
            const u16x8 v = *(const u16x8*)(&tsT[n * 256 + (c0 ^ swz(n))]);
            *(u16x8*)(xbt + ((size_t)b * N + nb * 64 + n) * C + c0) = v;
        }
    }
    // ---- phase B2: logits MFMA (wave wv owns m-block wv*16) ----
    const int wv = t >> 6, lane = t & 63, li = lane & 15, lk = lane >> 4;
    const f32x4 zv = {0.f, 0.f, 0.f, 0.f};
    f32x4 acc[4] = {zv, zv, zv, zv};
    const unsigned short* br = Wb + (size_t)(wv * 16 + li) * C + lk * 8;
#pragma unroll
    for (int c0 = 0; c0 < C; c0 += 32) {
        const s16x8 bfrag = *(const s16x8*)(br + c0);
#pragma unroll
        for (int s = 0; s < 4; ++s) {
            const int n = s * 16 + li;
            const s16x8 a = *(const s16x8*)(&tsT[n * 256 + ((lk * 8 + c0) ^ swz(n))]);
            acc[s] = MFMA(a, bfrag, acc[s]);
        }
    }
    unsigned short* Srow = Sb + ((size_t)b * M + wv * 16 + li) * N + nb * 64;
#pragma unroll
    for (int s = 0; s < 4; ++s) {
        u16x4 h;
#pragma unroll
        for (int r = 0; r < 4; ++r) h[r] = f2bf(acc[s][r]);
        *(u16x4*)(Srow + s * 16 + lk * 4) = h;
    }
}

// ---------------------------------------------------------------------------
// K2: softmax over n per (b,m); bf16 in -> bf16 out. (unchanged, verified)
// ---------------------------------------------------------------------------
__global__ __launch_bounds__(256) void k2_softmax_n(const unsigned short* __restrict__ Sb,
                                                    unsigned short* __restrict__ Pb) {
    const int m = blockIdx.x, b = blockIdx.y;
    const unsigned short* col = Sb + ((size_t)b * M + m) * N;
    unsigned short* po = Pb + ((size_t)b * M + m) * N;
    const int t = threadIdx.x;
    float v[16];
    const u16x8 h0 = *(const u16x8*)(col + t * 16);
    const u16x8 h1 = *(const u16x8*)(col + t * 16 + 8);
#pragma unroll
    for (int i = 0; i < 8; ++i) v[i] = bf2f(h0[i]);
#pragma unroll
    for (int i = 0; i < 8; ++i) v[8 + i] = bf2f(h1[i]);
    float mx = -INFINITY;
#pragma unroll
    for (int i = 0; i < 16; ++i) mx = fmaxf(mx, v[i]);
#pragma unroll
    for (int off = 32; off >= 1; off >>= 1) mx = fmaxf(mx, __shfl_xor(mx, off));
    __shared__ float redm[4], reds[4];
    const int wave = t >> 6, lane = t & 63;
    if (lane == 0) redm[wave] = mx;
    __syncthreads();
    mx = fmaxf(fmaxf(redm[0], redm[1]), fmaxf(redm[2], redm[3]));
    float s = 0.f;
#pragma unroll
    for (int i = 0; i < 16; ++i) {
        v[i] = __expf(v[i] - mx);
        s += v[i];
    }
#pragma unroll
    for (int off = 32; off >= 1; off >>= 1) s += __shfl_xor(s, off);
    if (lane == 0) reds[wave] = s;
    __syncthreads();
    s = reds[0] + reds[1] + reds[2] + reds[3];
    const float inv = 1.f / s;
    u16x8 o0, o1;
#pragma unroll
    for (int i = 0; i < 8; ++i) o0[i] = f2bf(v[i] * inv);
#pragma unroll
    for (int i = 0; i < 8; ++i) o1[i] = f2bf(v[8 + i] * inv);
    *(u16x8*)(po + t * 16) = o0;
    *(u16x8*)(po + t * 16 + 8) = o1;
}

// ---------------------------------------------------------------------------
// K3: proto partials parts[b][ck][m][c] over 512-n chunks.
// A = x f32 (c-rows, converted in-reg), B = Pbf (m-rows). f32x4 stores.
// ---------------------------------------------------------------------------
__global__ __launch_bounds__(256) void k3_mfma(const float* __restrict__ x,
                                               const unsigned short* __restrict__ Pb,
                                               float* __restrict__ parts) {
    const int ck = blockIdx.x, b = blockIdx.y;  // ck in [0,8)
    const int wv = threadIdx.x >> 6, lane = threadIdx.x & 63;
    const int li = lane & 15, lk = lane >> 4;
    const int c0w = wv * 64;
    const int nb = ck * 512;
    const f32x4 zv = {0.f, 0.f, 0.f, 0.f};
    f32x4 acc[4][4];
#pragma unroll
    for (int s = 0; s < 4; ++s)
#pragma unroll
        for (int u = 0; u < 4; ++u) acc[s][u] = zv;
    const float* ar = x + ((size_t)b * C + c0w + li) * N + nb + lk * 8;
    const unsigned short* br = Pb + ((size_t)b * M + li) * N + nb + lk * 8;
#pragma unroll 4
    for (int n0 = 0; n0 < 512; n0 += 32) {
        s16x8 af[4], bf_[4];
#pragma unroll
        for (int s = 0; s < 4; ++s) {
            const float* p = ar + (size_t)(s * 16) * N + n0;
            af[s] = cvt8(*(const f32x4*)p, *(const f32x4*)(p + 4));
        }
#pragma unroll
        for (int u = 0; u < 4; ++u) bf_[u] = *(const s16x8*)(br + (size_t)(u * 16) * N + n0);
#pragma unroll
        for (int s = 0; s < 4; ++s)
#pragma unroll
            for (int u = 0; u < 4; ++u) acc[s][u] = MFMA(af[s], bf_[u], acc[s][u]);
    }
    float* pp = parts + ((size_t)b * 8 + ck) * M * C;
#pragma unroll
    for (int s = 0; s < 4; ++s)
#pragma unroll
        for (int u = 0; u < 4; ++u)
            *(f32x4*)(pp + (size_t)(u * 16 + li) * C + c0w + s * 16 + lk * 4) = acc[s][u];
}

// ---------------------------------------------------------------------------
// K3b: reduce 8 chunks -> l2norm -> proto_bf [m][c], protoT_bf [c][m], p2.
// grid (8, B); block: 8 m x 256 c; 32-lane shfl for the c-norm.
// ---------------------------------------------------------------------------
__global__ __launch_bounds__(256) void k3b_reduce(const float* __restrict__ parts,
                                                  unsigned short* __restrict__ proto_bf,
                                                  unsigned short* __restrict__ protoT_bf,
                                                  float* __restrict__ p2) {
    const int mb = blockIdx.x, b = blockIdx.y;
    const int t = threadIdx.x;
    const int ml = t >> 5, cl = t & 31;
    const int m = mb * 8 + ml;
    const int c0 = cl * 8;
    float v[8] = {0.f, 0.f, 0.f, 0.f, 0.f, 0.f, 0.f, 0.f};
    const float* pbase = parts + (size_t)b * 8 * M * C + (size_t)m * C + c0;
#pragma unroll
    for (int ck = 0; ck < 8; ++ck) {
        const f32x4 q0 = *(const f32x4*)(pbase + (size_t)ck * M * C);
        const f32x4 q1 = *(const f32x4*)(pbase + (size_t)ck * M * C + 4);
#pragma unroll
        for (int j = 0; j < 4; ++j) { v[j] += q0[j]; v[4 + j] += q1[j]; }
    }
    float sq = 0.f;
#pragma unroll
    for (int j = 0; j < 8; ++j) sq += v[j] * v[j];
#pragma unroll
    for (int off = 16; off >= 1; off >>= 1) sq += __shfl_xor(sq, off);
    const float denom = fmaxf(sqrtf(sq), EPS);
    const float scale = 1.f / denom;
    if (cl == 0) p2[b * M + m] = sq / (denom * denom);
    u16x8 h;
#pragma unroll
    for (int j = 0; j < 8; ++j) h[j] = f2bf(v[j] * scale);
    *(u16x8*)(proto_bf + ((size_t)b * M + m) * C + c0) = h;
#pragma unroll
    for (int j = 0; j < 8; ++j)
        protoT_bf[((size_t)b * C + c0 + j) * M + m] = h[j];
}

// ---------------------------------------------------------------------------
// K4: fused score + softmax-over-m + compact partials.
// A = proto_bf (m-rows), B = xbt (n-rows): lane group (4 lk-lanes) holds all
// 64 m for a pixel -> softmax via shfl_xor(16/32). Writes pnm bf16 [b][n][m].
// ---------------------------------------------------------------------------
__global__ __launch_bounds__(256) void k4_score(const unsigned short* __restrict__ proto_bf,
                                                const unsigned short* __restrict__ xbt,
                                                const float* __restrict__ p2,
                                                const float* __restrict__ xsq,
                                                unsigned short* __restrict__ pnm,
                                                float* __restrict__ cparts) {
    const int b = blockIdx.y;
    const int wv = threadIdx.x >> 6, lane = threadIdx.x & 63;
    const int li = lane & 15, lk = lane >> 4;
    const int nbase = blockIdx.x * 256 + wv * 64;
    const f32x4 zv = {0.f, 0.f, 0.f, 0.f};
    f32x4 acc[4][4];  // [s: m-sub][u: n-sub]
#pragma unroll
    for (int s = 0; s < 4; ++s)
#pragma unroll
        for (int u = 0; u < 4; ++u) acc[s][u] = zv;
    const unsigned short* ar = proto_bf + ((size_t)b * M + li) * C + lk * 8;
    const unsigned short* br = xbt + ((size_t)b * N + nbase + li) * C + lk * 8;
#pragma unroll
    for (int c0 = 0; c0 < C; c0 += 32) {
        s16x8 af[4], bf_[4];
#pragma unroll
        for (int s = 0; s < 4; ++s) af[s] = *(const s16x8*)(ar + (size_t)(s * 16) * C + c0);
#pragma unroll
        for (int u = 0; u < 4; ++u) bf_[u] = *(const s16x8*)(br + (size_t)(u * 16) * C + c0);
#pragma unroll
        for (int s = 0; s < 4; ++s)
#pragma unroll
            for (int u = 0; u < 4; ++u) acc[s][u] = MFMA(af[s], bf_[u], acc[s][u]);
    }
    float csum = 0.f;
#pragma unroll
    for (int u = 0; u < 4; ++u) {
        const int n = nbase + u * 16 + li;
        float vmax = -INFINITY;
#pragma unroll
        for (int s = 0; s < 4; ++s)
#pragma unroll
            for (int r = 0; r < 4; ++r) vmax = fmaxf(vmax, acc[s][u][r]);
        vmax = fmaxf(vmax, __shfl_xor(vmax, 16));
        vmax = fmaxf(vmax, __shfl_xor(vmax, 32));
        int t1 = 1 << 30;
#pragma unroll
        for (int s = 0; s < 4; ++s)
#pragma unroll
            for (int r = 0; r < 4; ++r)
                if (acc[s][u][r] == vmax) t1 = min(t1, s * 16 + lk * 4 + r);
        t1 = min(t1, __shfl_xor(t1, 16));
        t1 = min(t1, __shfl_xor(t1, 32));
        float es = 0.f;
#pragma unroll
        for (int s = 0; s < 4; ++s)
#pragma unroll
            for (int r = 0; r < 4; ++r) {
                const float e = __expf(acc[s][u][r] - vmax);
                acc[s][u][r] = e;
                es += e;
            }
        es += __shfl_xor(es, 16);
        es += __shfl_xor(es, 32);
        const float inv = 1.f / es;
        unsigned short* prow = pnm + ((size_t)b * N + n) * M;
#pragma unroll
        for (int s = 0; s < 4; ++s) {
            u16x4 h;
#pragma unroll
            for (int r = 0; r < 4; ++r) h[r] = f2bf(acc[s][u][r] * inv);
            *(u16x4*)(prow + s * 16 + lk * 4) = h;
        }
        if (lk == 0) csum += xsq[(size_t)b * N + n] - 2.f * vmax + p2[b * M + t1];
    }
#pragma unroll
    for (int off = 32; off >= 1; off >>= 1) csum += __shfl_xor(csum, off);
    __shared__ float red[4];
    if (lane == 0) red[wv] = csum;
    __syncthreads();
    if (threadIdx.x == 0)
        cparts[b * 16 + blockIdx.x] = red[0] + red[1] + red[2] + red[3];
}

// ---------------------------------------------------------------------------
// K4b: out[b][c][n] = l2norm_c(sum_m p[n][m]*protoT[c][m]).
// A = pnm (n-rows), B = protoT (c-rows): per-lane f32x4 is n-contiguous
// -> vectorized output stores. Cross-lane/wave c-norm via shfl + LDS.
// ---------------------------------------------------------------------------
__global__ __launch_bounds__(256) void k4b_mfma(const unsigned short* __restrict__ pnm,
                                                const unsigned short* __restrict__ protoT_bf,
                                                float* __restrict__ out) {
    const int b = blockIdx.y;
    const int wv = threadIdx.x >> 6, lane = threadIdx.x & 63;
    const int li = lane & 15, lk = lane >> 4;
    const int n0 = blockIdx.x * 64;
    const int cb = wv * 64;
    const f32x4 zv = {0.f, 0.f, 0.f, 0.f};
    f32x4 acc[4][4];  // [s: n-sub][u: c-sub]
#pragma unroll
    for (int s = 0; s < 4; ++s)
#pragma unroll
        for (int u = 0; u < 4; ++u) acc[s][u] = zv;
    const unsigned short* ar = pnm + ((size_t)b * N + n0 + li) * M + lk * 8;
    const unsigned short* br = protoT_bf + ((size_t)b * C + cb + li) * M + lk * 8;
#pragma unroll
    for (int m0 = 0; m0 < M; m0 += 32) {
        s16x8 af[4], bf_[4];
#pragma unroll
        for (int s = 0; s < 4; ++s) af[s] = *(const s16x8*)(ar + (size_t)(s * 16) * M + m0);
#pragma unroll
        for (int u = 0; u < 4; ++u) bf_[u] = *(const s16x8*)(br + (size_t)(u * 16) * M + m0);
#pragma unroll
        for (int s = 0; s < 4; ++s)
#pragma unroll
            for (int u = 0; u < 4; ++u) acc[s][u] = MFMA(af[s], bf_[u], acc[s][u]);
    }
    // c-norm per n: n = n0 + s*16 + lk*4 + r; c = cb + u*16 + li
    __shared__ float ls[4][64];
    __shared__ float ls2[64];
    float psq[4][4];
#pragma unroll
    for (int s = 0; s < 4; ++s)
#pragma unroll
        for (int r = 0; r < 4; ++r) {
            float sum = 0.f;
#pragma unroll
            for (int u = 0; u < 4; ++u) sum += acc[s][u][r] * acc[s][u][r];
#pragma unroll
            for (int off = 8; off >= 1; off >>= 1) sum += __shfl_xor(sum, off);
            psq[s][r] = sum;
        }
    if (li == 0) {
#pragma unroll
        for (int s = 0; s < 4; ++s)
#pragma unroll
            for (int r = 0; r < 4; ++r) ls[wv][s * 16 + lk * 4 + r] = psq[s][r];
    }
    __syncthreads();
    if (threadIdx.x < 64) {
        const int tt = threadIdx.x;
        const float tot = ls[0][tt] + ls[1][tt] + ls[2][tt] + ls[3][tt];
        ls2[tt] = 1.f / fmaxf(sqrtf(tot), EPS);
    }
    __syncthreads();
    float scl[4][4];
#pragma unroll
    for (int s = 0; s < 4; ++s)
#pragma unroll
        for (int r = 0; r < 4; ++r) scl[s][r] = ls2[s * 16 + lk * 4 + r];
    float* ob = out + (size_t)b * C * N;
#pragma unroll
    for (int s = 0; s < 4; ++s)
#pragma unroll
        for (int u = 0; u < 4; ++u) {
            f32x4 q;
#pragma unroll
            for (int r = 0; r < 4; ++r) q[r] = acc[s][u][r] * scl[s][r];
            *(f32x4*)(ob + (size_t)(cb + u * 16 + li) * N + n0 + s * 16 + lk * 4) = q;
        }
}

// ---------------------------------------------------------------------------
// K5: distance loss partials; proto_bf staged to f32 LDS with XOR swizzle.
// ---------------------------------------------------------------------------
__global__ __launch_bounds__(256) void k5_dis(const unsigned short* __restrict__ proto_bf,
                                              const float* __restrict__ p2,
                                              float* __restrict__ dparts) {
    const int q = blockIdx.x;
    const int b = blockIdx.y;
    const unsigned short* pr = proto_bf + (size_t)b * M * C;
    __shared__ float pl[M * C];  // 64 KB
    for (int idx = threadIdx.x; idx < M * C; idx += 256) {
        int m = idx >> 8, c = idx & 255;
        pl[m * 256 + (c ^ (m & 31))] = bf2f(pr[idx]);
    }
    __syncthreads();
    float sum = 0.f;
    for (int k = 0; k < 2; ++k) {
        const int pair = q * 512 + k * 256 + threadIdx.x;
        const int i = pair >> 6, j = pair & 63;
        if (j > i) {
            float g = 0.f;
#pragma unroll 8
            for (int c = 0; c < C; ++c)
                g += pl[i * 256 + (c ^ (i & 31))] * pl[j * 256 + (c ^ (j & 31))];
            const float d = 1.f - (p2[b * M + i] + p2[b * M + j] - 2.f * g);
            sum += fmaxf(d, 0.f);
        }
    }
#pragma unroll
    for (int off = 32; off >= 1; off >>= 1) sum += __shfl_xor(sum, off);
    __shared__ float red[4];
    const int wave = threadIdx.x >> 6, lane = threadIdx.x & 63;
    if (lane == 0) red[wave] = sum;
    __syncthreads();
    if (threadIdx.x == 0) dparts[b * 8 + q] = red[0] + red[1] + red[2] + red[3];
}

__global__ __launch_bounds__(256) void k6_final(const float* __restrict__ cparts,
                                                const float* __restrict__ dparts,
                                                float* __restrict__ losses) {
    const int t = threadIdx.x;
    float cs = cparts[t] + cparts[t + 256];
    float ds = dparts[t];
#pragma unroll
    for (int off = 32; off >= 1; off >>= 1) {
        cs += __shfl_xor(cs, off);
        ds += __shfl_xor(ds, off);
    }
    __shared__ float rc[4], rd[4];
    const int wave = t >> 6, lane = t & 63;
    if (lane == 0) { rc[wave] = cs; rd[wave] = ds; }
    __syncthreads();
    if (t == 0) {
        const float ctot = rc[0] + rc[1] + rc[2] + rc[3];
        const float dtot = rd[0] + rd[1] + rd[2] + rd[3];
        losses[0] = ctot / ((float)B * (float)N * (float)C);
        losses[1] = dtot * (2.f / (float)(M * (M - 1))) / (float)B;
    }
}

extern "C" void kernel_launch(void* const* d_in, const int* in_sizes, int n_in,
                              void* d_out, int out_size, void* d_ws, size_t ws_size,
                              hipStream_t stream) {
    const float* x = (const float*)d_in[0];
    const float* Wf = (const float*)d_in[1];
    float* out = (float*)d_out;

    // ---- d_out as scratch ----
    // xbt bf16 [b][n][c]: floats [0, 16,777,216) -- live k01..k4 (dead before k4b)
    unsigned short* xbt = (unsigned short*)d_out;
    float* losses = out + (size_t)B * C * N;

    // ---- ws layout (floats), non-overlapping regions, 34.5 MB total ----
    float* wsf = (float*)d_ws;
    // region A [0, 4,194,304): Sbf bf16 (k01->k2), then parts f32 (k3->k3b)
    unsigned short* Sbf = (unsigned short*)wsf;
    float* parts = wsf;
    // region B [4,194,304, 8,388,608): Pbf bf16 (k2->k3), then pnm bf16 (k4->k4b)
    unsigned short* Pbf = (unsigned short*)(wsf + 4194304);
    unsigned short* pnm = Pbf;
    float* xsq = wsf + 8388608;                                    // 131,072 f
    unsigned short* proto_bf = (unsigned short*)(wsf + 8519680);   // 262,144 f
    unsigned short* protoT_bf = (unsigned short*)(wsf + 8781824);  // 262,144 f
    unsigned short* Wb = (unsigned short*)(wsf + 9043968);         // 8,192 f
    float* p2 = wsf + 9052160;                                     // 2,048 f
    float* cparts = wsf + 9054208;                                 // 512 f
    float* dparts = wsf + 9054720;                                 // 256 f

    kW_convert<<<dim3(64), 256, 0, stream>>>(Wf, Wb);
    k01<<<dim3(N / 64, B), 256, 0, stream>>>(x, Wb, xbt, Sbf, xsq);
    k2_softmax_n<<<dim3(M, B), 256, 0, stream>>>(Sbf, Pbf);
    k3_mfma<<<dim3(8, B), 256, 0, stream>>>(x, Pbf, parts);
    k3b_reduce<<<dim3(8, B), 256, 0, stream>>>(parts, proto_bf, protoT_bf, p2);
    k4_score<<<dim3(N / 256, B), 256, 0, stream>>>(proto_bf, xbt, p2, xsq, pnm, cparts);
    k4b_mfma<<<dim3(N / 64, B), 256, 0, stream>>>(pnm, protoT_bf, out);
    k5_dis<<<dim3(8, B), 256, 0, stream>>>(proto_bf, p2, dparts);
    k6_final<<<1, 256, 0, stream>>>(cparts, dparts, losses);
}